// Round 1
// baseline (320.700 us; speedup 1.0000x reference)
//
#include <hip/hip_runtime.h>

namespace {
constexpr int B_ = 64, S_ = 200, DV_ = 128, NC2_ = 4096;
constexpr int CHUNK = 25, NCH = 8;  // 8*25 = 200
}

// ---------------------------------------------------------------------------
// Kernel 1: blocks [0,64): GRU recurrence per batch (writes h_seq)
//           blocks [64,128): C2 scalar-scan per batch (writes vals_ws[B*S])
// ---------------------------------------------------------------------------
__global__ __launch_bounds__(384) void k1_gru_vals(
    const int* __restrict__ c2_seq, const int* __restrict__ d_seq,
    const int* __restrict__ r_seq, const float* __restrict__ D_emb,
    const float* __restrict__ v_d, const float* __restrict__ v_c2,
    const float* __restrict__ R_emb,
    const float* __restrict__ W_ih, const float* __restrict__ W_hh,
    const float* __restrict__ b_ih, const float* __restrict__ b_hh,
    const float* __restrict__ W3, const float* __restrict__ b3,
    const float* __restrict__ W4, const float* __restrict__ b4,
    float* __restrict__ out_h, float* __restrict__ vals_ws)
{
  const int tid = threadIdx.x;
  if (blockIdx.x < B_) {
    // ------------------ GRU for batch b ------------------
    const int b = blockIdx.x;
    __shared__ float4 h4[DV_ / 4];
    __shared__ float s_rz[2 * DV_];
    __shared__ float s_xn[DV_], s_hn[DV_];
    __shared__ float gl[S_];
    __shared__ int rl[S_];
    float* h = reinterpret_cast<float*>(h4);

    for (int i = tid; i < S_; i += 384) {
      gl[i] = D_emb[d_seq[b * S_ + i]];
      rl[i] = r_seq[b * S_ + i];
    }
    const int g = tid;  // 0..383 : output row of the 384x128 recurrent matvec
    // W_hh row in registers
    float w[DV_];
    {
      const float4* wr = reinterpret_cast<const float4*>(W_hh + (size_t)g * DV_);
#pragma unroll
      for (int k = 0; k < DV_ / 4; ++k) {
        float4 t = wr[k];
        w[4 * k] = t.x; w[4 * k + 1] = t.y; w[4 * k + 2] = t.z; w[4 * k + 3] = t.w;
      }
    }
    // collapsed input projections: xW[g] = gamma*u + p_{r}  (p includes b_ih)
    float u = 0.f, p0 = 0.f, p1 = 0.f;
    {
      const float4* wi = reinterpret_cast<const float4*>(W_ih + (size_t)g * 2 * DV_);
      const float4* vd4 = reinterpret_cast<const float4*>(v_d);
      const float4* re4 = reinterpret_cast<const float4*>(R_emb);
#pragma unroll 8
      for (int k = 0; k < DV_ / 4; ++k) {
        float4 a = wi[k], vv = vd4[k];
        u += a.x * vv.x + a.y * vv.y + a.z * vv.z + a.w * vv.w;
      }
#pragma unroll 8
      for (int k = 0; k < DV_ / 4; ++k) {
        float4 a = wi[DV_ / 4 + k];
        float4 r0 = re4[k], r1 = re4[DV_ / 4 + k];
        p0 += a.x * r0.x + a.y * r0.y + a.z * r0.z + a.w * r0.w;
        p1 += a.x * r1.x + a.y * r1.y + a.z * r1.z + a.w * r1.w;
      }
      float bi = b_ih[g];
      p0 += bi; p1 += bi;
    }
    const float bhh = b_hh[g];
    if (tid < DV_) h[tid] = 0.f;
    __syncthreads();

    for (int t = 0; t < S_; ++t) {
      const float xw = gl[t] * u + (rl[t] ? p1 : p0);
      float a0 = 0, a1 = 0, a2 = 0, a3 = 0;
#pragma unroll
      for (int k = 0; k < DV_ / 4; ++k) {
        float4 hv = h4[k];  // uniform address -> LDS broadcast
        a0 += w[4 * k + 0] * hv.x; a1 += w[4 * k + 1] * hv.y;
        a2 += w[4 * k + 2] * hv.z; a3 += w[4 * k + 3] * hv.w;
      }
      const float hwv = (a0 + a1) + (a2 + a3) + bhh;
      if (g < 2 * DV_) s_rz[g] = xw + hwv;
      else { s_xn[g - 2 * DV_] = xw; s_hn[g - 2 * DV_] = hwv; }
      __syncthreads();
      if (tid < DV_) {
        const float r = 1.f / (1.f + __expf(-s_rz[tid]));
        const float z = 1.f / (1.f + __expf(-s_rz[DV_ + tid]));
        const float nx = s_xn[tid] + r * s_hn[tid];
        const float e2 = __expf(2.f * nx);
        const float n = (e2 - 1.f) / (e2 + 1.f);
        const float hnew = (1.f - z) * n + z * h[tid];
        h[tid] = hnew;
        out_h[((size_t)(b * S_ + t)) * DV_ + tid] = hnew;
      }
      __syncthreads();
    }
  } else {
    // ------------------ C2 value scan for batch b ------------------
    const int b = blockIdx.x - B_;
    __shared__ float C2s[NC2_];
    __shared__ float red[2];
    __shared__ float gl[S_];
    __shared__ int rl[S_];
    __shared__ int jl[S_];
    for (int i = tid; i < S_; i += 384) {
      gl[i] = D_emb[d_seq[b * S_ + i]];
      rl[i] = r_seq[b * S_ + i];
      jl[i] = c2_seq[b * S_ + i];
    }
    float a3v = 0, u3v = 0, q0 = 0, q1 = 0, w4v = 0;
    if (tid < DV_) {
      // W3 row of length 384 = [c2-part | d-part | r-part], as 96 float4s
      const float4* w3r = reinterpret_cast<const float4*>(W3 + (size_t)tid * 3 * DV_);
      const float4* vc4 = reinterpret_cast<const float4*>(v_c2);
      const float4* vd4 = reinterpret_cast<const float4*>(v_d);
      const float4* re4 = reinterpret_cast<const float4*>(R_emb);
#pragma unroll 8
      for (int k = 0; k < DV_ / 4; ++k) {
        float4 a = w3r[k], cc = vc4[k];
        a3v += a.x * cc.x + a.y * cc.y + a.z * cc.z + a.w * cc.w;
        float4 bq = w3r[DV_ / 4 + k], dd = vd4[k];
        u3v += bq.x * dd.x + bq.y * dd.y + bq.z * dd.z + bq.w * dd.w;
        float4 cq = w3r[2 * (DV_ / 4) + k];
        float4 r0 = re4[k], r1 = re4[DV_ / 4 + k];
        q0 += cq.x * r0.x + cq.y * r0.y + cq.z * r0.z + cq.w * r0.w;
        q1 += cq.x * r1.x + cq.y * r1.y + cq.z * r1.z + cq.w * r1.w;
      }
      float bb = b3[tid];
      q0 += bb; q1 += bb;
      w4v = W4[tid];
    }
    const float b4v = b4[0];
    for (int i = tid; i < NC2_; i += 384) C2s[i] = 0.f;
    __syncthreads();
    for (int t = 0; t < S_; ++t) {
      const int j = jl[t];
      float part = 0.f;
      if (tid < DV_) {
        const float beta = C2s[j];
        float h3 = beta * a3v + gl[t] * u3v + (rl[t] ? q1 : q0);
        h3 = fmaxf(h3, 0.f);
        part = w4v * h3;
      }
#pragma unroll
      for (int off = 1; off < 64; off <<= 1) part += __shfl_xor(part, off);
      if (tid == 0) red[0] = part;
      else if (tid == 64) red[1] = part;
      __syncthreads();
      if (tid == 0) {
        const float val = red[0] + red[1] + b4v;
        C2s[j] = val;
        vals_ws[b * S_ + t] = val;
      }
      __syncthreads();
    }
  }
}

// ---------------------------------------------------------------------------
// Kernel 2: blocks [0,64): alpha MLP per batch (reads h_seq)
//           blocks [64,576): C2_seq fill, 8 chunks of 25 steps per batch
// ---------------------------------------------------------------------------
__global__ __launch_bounds__(256) void k2_alpha_fill(
    const int* __restrict__ c2_seq,
    const float* __restrict__ W1, const float* __restrict__ b1,
    const float* __restrict__ W2, const float* __restrict__ b2,
    const float* __restrict__ vals_ws, const float* __restrict__ h_seq,
    float* __restrict__ out_alpha, float* __restrict__ out_c2)
{
  const int tid = threadIdx.x;
  if (blockIdx.x < B_) {
    // ------------------ alpha for batch b ------------------
    const int b = blockIdx.x;
    __shared__ float4 hb4[2][DV_ / 4];
    __shared__ float red[4];
    const int grp = tid >> 7, d = tid & 127;
    float w1r[DV_];
    {
      const float4* wr = reinterpret_cast<const float4*>(W1 + (size_t)d * DV_);
#pragma unroll
      for (int k = 0; k < DV_ / 4; ++k) {
        float4 t = wr[k];
        w1r[4 * k] = t.x; w1r[4 * k + 1] = t.y; w1r[4 * k + 2] = t.z; w1r[4 * k + 3] = t.w;
      }
    }
    const float b1v = b1[d], w2v = W2[d], b2v = b2[0];
    float* hb = reinterpret_cast<float*>(hb4[grp]);
    for (int s = 0; s < S_; s += 2) {
      const int ss = s + grp;
      hb[d] = h_seq[((size_t)(b * S_ + ss)) * DV_ + d];
      __syncthreads();
      float y0 = b1v, y1 = 0, y2 = 0, y3 = 0;
#pragma unroll
      for (int k = 0; k < DV_ / 4; ++k) {
        float4 hv = hb4[grp][k];
        y0 += w1r[4 * k + 0] * hv.x; y1 += w1r[4 * k + 1] * hv.y;
        y2 += w1r[4 * k + 2] * hv.z; y3 += w1r[4 * k + 3] * hv.w;
      }
      float part = w2v * fmaxf((y0 + y1) + (y2 + y3), 0.f);
#pragma unroll
      for (int off = 1; off < 64; off <<= 1) part += __shfl_xor(part, off);
      if ((tid & 63) == 0) red[tid >> 6] = part;
      __syncthreads();
      if (d == 0) out_alpha[b * S_ + ss] = red[2 * grp] + red[2 * grp + 1] + b2v;
      __syncthreads();
    }
  } else {
    // ------------------ C2_seq fill ------------------
    const int blk = blockIdx.x - B_;
    const int b = blk >> 3, c = blk & 7;
    const int s0 = c * CHUNK, s1 = s0 + CHUNK;
    __shared__ float C2s[NC2_];
    __shared__ int owner[NC2_];
    __shared__ float vls[S_];
    __shared__ int jl[S_];
    for (int i = tid; i < NC2_; i += 256) { C2s[i] = 0.f; owner[i] = -1; }
    for (int i = tid; i < S_; i += 256) {
      vls[i] = vals_ws[b * S_ + i];
      jl[i] = c2_seq[b * S_ + i];
    }
    __syncthreads();
    // last-writer-wins replay of events t < s0 (parallel)
    for (int t = tid; t < s0; t += 256) atomicMax(&owner[jl[t]], t);
    __syncthreads();
    for (int t = tid; t < s0; t += 256)
      if (owner[jl[t]] == t) C2s[jl[t]] = vls[t];
    __syncthreads();
    float* dst = out_c2 + (size_t)b * S_ * NC2_;
    for (int s = s0; s < s1; ++s) {
      if (tid == 0) C2s[jl[s]] = vls[s];
      __syncthreads();
      float4* drow = reinterpret_cast<float4*>(dst + (size_t)s * NC2_);
      const float4* srow = reinterpret_cast<const float4*>(C2s);
#pragma unroll
      for (int jj = 0; jj < 4; ++jj) drow[tid + jj * 256] = srow[tid + jj * 256];
      __syncthreads();
    }
  }
}

extern "C" void kernel_launch(void* const* d_in, const int* in_sizes, int n_in,
                              void* d_out, int out_size, void* d_ws, size_t ws_size,
                              hipStream_t stream) {
  const int* c2_seq = (const int*)d_in[1];
  const int* d_seq = (const int*)d_in[3];
  const int* r_seq = (const int*)d_in[4];
  const float* D_emb = (const float*)d_in[5];
  const float* v_d = (const float*)d_in[6];
  const float* v_c2 = (const float*)d_in[7];
  const float* R_emb = (const float*)d_in[8];
  const float* W_ih = (const float*)d_in[9];
  const float* W_hh = (const float*)d_in[10];
  const float* b_ih = (const float*)d_in[11];
  const float* b_hh = (const float*)d_in[12];
  const float* W1 = (const float*)d_in[13];
  const float* b1 = (const float*)d_in[14];
  const float* W2 = (const float*)d_in[15];
  const float* b2 = (const float*)d_in[16];
  const float* W3 = (const float*)d_in[17];
  const float* b3 = (const float*)d_in[18];
  const float* W4 = (const float*)d_in[19];
  const float* b4 = (const float*)d_in[20];

  float* out = (float*)d_out;
  float* out_alpha = out;                                  // [B,S]
  float* out_h = out + B_ * S_;                            // [B,S,DV]
  float* out_c2 = out + B_ * S_ + (size_t)B_ * S_ * DV_;   // [B,S,NC2]
  float* vals_ws = (float*)d_ws;                           // [B*S] floats

  k1_gru_vals<<<dim3(2 * B_), dim3(384), 0, stream>>>(
      c2_seq, d_seq, r_seq, D_emb, v_d, v_c2, R_emb, W_ih, W_hh, b_ih, b_hh,
      W3, b3, W4, b4, out_h, vals_ws);
  k2_alpha_fill<<<dim3(B_ + B_ * NCH), dim3(256), 0, stream>>>(
      c2_seq, W1, b1, W2, b2, vals_ws, out_h, out_alpha, out_c2);
}

// Round 2
// 289.672 us; speedup vs baseline: 1.1071x; 1.1071x over previous
//
#include <hip/hip_runtime.h>

namespace {
constexpr int B_ = 64, S_ = 200, DV_ = 128, NC2_ = 4096;
constexpr int FCH = 10, NFCH = 20;   // fill: 20 chunks x 10 rows
constexpr int ACH = 50, NACH = 4;    // alpha: 4 chunks x 50 rows
}

typedef float f4v __attribute__((ext_vector_type(4)));

// ---------------------------------------------------------------------------
// K1: blocks [0,64):  GRU per batch, 768 threads, 2-way K-split per row
//     blocks [64,128): C2 value scan per batch, single wave, barrier-free
// ---------------------------------------------------------------------------
__global__ __launch_bounds__(768) void k1_gru_scan(
    const int* __restrict__ c2_seq, const int* __restrict__ d_seq,
    const int* __restrict__ r_seq, const float* __restrict__ D_emb,
    const float* __restrict__ v_d, const float* __restrict__ v_c2,
    const float* __restrict__ R_emb,
    const float* __restrict__ W_ih, const float* __restrict__ W_hh,
    const float* __restrict__ b_ih, const float* __restrict__ b_hh,
    const float* __restrict__ W3, const float* __restrict__ b3,
    const float* __restrict__ W4, const float* __restrict__ b4,
    float* __restrict__ out_h, float* __restrict__ vals_ws)
{
  const int tid = threadIdx.x;
  if (blockIdx.x < B_) {
    // ------------------ GRU for batch b ------------------
    const int b = blockIdx.x;
    __shared__ float4 h4[DV_ / 4];
    __shared__ float s_rz[2 * DV_];
    __shared__ float s_xn[DV_], s_hn[DV_];
    __shared__ float gl[S_];
    __shared__ int rl[S_];
    float* h = reinterpret_cast<float*>(h4);

    for (int i = tid; i < S_; i += 768) {
      gl[i] = D_emb[d_seq[b * S_ + i]];
      rl[i] = r_seq[b * S_ + i];
    }
    const int g = tid >> 1;   // output row 0..383
    const int p = tid & 1;    // K-half
    // W_hh half-row in registers (64 floats)
    float w[64];
    {
      const float4* wr =
          reinterpret_cast<const float4*>(W_hh + (size_t)g * DV_ + p * 64);
#pragma unroll
      for (int k = 0; k < 16; ++k) {
        float4 t4 = wr[k];
        w[4 * k] = t4.x; w[4 * k + 1] = t4.y;
        w[4 * k + 2] = t4.z; w[4 * k + 3] = t4.w;
      }
    }
    // collapsed input projection: xw[g] = gamma*u + p_{r}  (includes b_ih)
    float u = 0.f, p0 = 0.f, p1 = 0.f;
    {
      const float4* wi = reinterpret_cast<const float4*>(W_ih + (size_t)g * 2 * DV_);
      const float4* vd4 = reinterpret_cast<const float4*>(v_d);
      const float4* re4 = reinterpret_cast<const float4*>(R_emb);
#pragma unroll 8
      for (int k = 0; k < DV_ / 4; ++k) {
        float4 a = wi[k], vv = vd4[k];
        u += a.x * vv.x + a.y * vv.y + a.z * vv.z + a.w * vv.w;
      }
#pragma unroll 8
      for (int k = 0; k < DV_ / 4; ++k) {
        float4 a = wi[DV_ / 4 + k];
        float4 r0 = re4[k], r1 = re4[DV_ / 4 + k];
        p0 += a.x * r0.x + a.y * r0.y + a.z * r0.z + a.w * r0.w;
        p1 += a.x * r1.x + a.y * r1.y + a.z * r1.z + a.w * r1.w;
      }
      float bi = b_ih[g];
      p0 += bi; p1 += bi;
    }
    const float bhh = b_hh[g];
    if (tid < DV_) h[tid] = 0.f;
    __syncthreads();

    for (int t = 0; t < S_; ++t) {
      const float xw = gl[t] * u + (rl[t] ? p1 : p0);
      float a0 = 0, a1 = 0, a2 = 0, a3 = 0;
#pragma unroll
      for (int k = 0; k < 16; ++k) {
        float4 hv = h4[p * 16 + k];  // 2-address broadcast (free)
        a0 += w[4 * k + 0] * hv.x; a1 += w[4 * k + 1] * hv.y;
        a2 += w[4 * k + 2] * hv.z; a3 += w[4 * k + 3] * hv.w;
      }
      float s = (a0 + a1) + (a2 + a3);
      s += __shfl_xor(s, 1);   // combine K-halves (adjacent lanes)
      if (p == 0) {
        const float hwv = s + bhh;
        if (g < 2 * DV_) s_rz[g] = xw + hwv;
        else { s_xn[g - 2 * DV_] = xw; s_hn[g - 2 * DV_] = hwv; }
      }
      __syncthreads();
      if (tid < DV_) {
        const float r = 1.f / (1.f + __expf(-s_rz[tid]));
        const float z = 1.f / (1.f + __expf(-s_rz[DV_ + tid]));
        const float nx = s_xn[tid] + r * s_hn[tid];
        const float e2 = __expf(2.f * nx);
        const float n = (e2 - 1.f) / (e2 + 1.f);
        const float hnew = (1.f - z) * n + z * h[tid];
        h[tid] = hnew;
        out_h[((size_t)(b * S_ + t)) * DV_ + tid] = hnew;
      }
      __syncthreads();
    }
  } else {
    // ------------------ C2 value scan, single wave ------------------
    const int b = blockIdx.x - B_;
    __shared__ float C2s[NC2_];
    __shared__ float gl[S_];
    __shared__ int rl[S_];
    __shared__ int jl[S_];
    for (int i = tid; i < NC2_; i += 768) C2s[i] = 0.f;
    for (int i = tid; i < S_; i += 768) {
      gl[i] = D_emb[d_seq[b * S_ + i]];
      rl[i] = r_seq[b * S_ + i];
      jl[i] = c2_seq[b * S_ + i];
    }
    __syncthreads();
    if (tid >= 64) return;
    const int lane = tid;
    // coefficients for d = lane and d = lane+64
    float a3L = 0, u3L = 0, q0L = 0, q1L = 0;
    float a3H = 0, u3H = 0, q0H = 0, q1H = 0;
    {
      const float4* vc4 = reinterpret_cast<const float4*>(v_c2);
      const float4* vd4 = reinterpret_cast<const float4*>(v_d);
      const float4* re4 = reinterpret_cast<const float4*>(R_emb);
      const float4* wL = reinterpret_cast<const float4*>(W3 + (size_t)lane * 3 * DV_);
      const float4* wH = reinterpret_cast<const float4*>(W3 + (size_t)(lane + 64) * 3 * DV_);
#pragma unroll 8
      for (int k = 0; k < DV_ / 4; ++k) {
        float4 cc = vc4[k], dd = vd4[k];
        float4 r0 = re4[k], r1 = re4[DV_ / 4 + k];
        float4 aL = wL[k], aH = wH[k];
        a3L += aL.x * cc.x + aL.y * cc.y + aL.z * cc.z + aL.w * cc.w;
        a3H += aH.x * cc.x + aH.y * cc.y + aH.z * cc.z + aH.w * cc.w;
        float4 bL = wL[DV_ / 4 + k], bH = wH[DV_ / 4 + k];
        u3L += bL.x * dd.x + bL.y * dd.y + bL.z * dd.z + bL.w * dd.w;
        u3H += bH.x * dd.x + bH.y * dd.y + bH.z * dd.z + bH.w * dd.w;
        float4 cL = wL[2 * (DV_ / 4) + k], cH = wH[2 * (DV_ / 4) + k];
        q0L += cL.x * r0.x + cL.y * r0.y + cL.z * r0.z + cL.w * r0.w;
        q1L += cL.x * r1.x + cL.y * r1.y + cL.z * r1.z + cL.w * r1.w;
        q0H += cH.x * r0.x + cH.y * r0.y + cH.z * r0.z + cH.w * r0.w;
        q1H += cH.x * r1.x + cH.y * r1.y + cH.z * r1.z + cH.w * r1.w;
      }
      float bbL = b3[lane], bbH = b3[lane + 64];
      q0L += bbL; q1L += bbL; q0H += bbH; q1H += bbH;
    }
    const float w4L = W4[lane], w4H = W4[lane + 64];
    const float b4v = b4[0];

    // software-pipelined scan: prefetch state + scalars one step ahead
    int jc = jl[0];
    float gv = gl[0];
    int rv = rl[0];
    float pf = 0.f;          // beta for t=0 (state is zero)
    float lastv = 0.f;
    int lastj = -1;
    for (int t = 0; t < S_; ++t) {
      const int tn = (t + 1 < S_) ? t + 1 : 0;
      const int jn = jl[tn];
      const float gvn = gl[tn];
      const int rvn = rl[tn];
      const float pfn = C2s[jn];   // issued before this step's write; patched below
      const float beta = (jc == lastj) ? lastv : pf;
      float hL = beta * a3L + gv * u3L + (rv ? q1L : q0L);
      float hH = beta * a3H + gv * u3H + (rv ? q1H : q0H);
      float part = fmaxf(hL, 0.f) * w4L + fmaxf(hH, 0.f) * w4H;
#pragma unroll
      for (int off = 1; off < 64; off <<= 1) part += __shfl_xor(part, off);
      const float val = part + b4v;
      if (lane == 0) {
        C2s[jc] = val;
        vals_ws[b * S_ + t] = val;
      }
      lastj = jc; lastv = val;
      jc = jn; gv = gvn; rv = rvn; pf = pfn;
    }
  }
}

// ---------------------------------------------------------------------------
// K2: blocks [0,256):    alpha MLP, (b, 50-row chunk)
//     blocks [256,1536): C2_seq fill, (b, 10-row chunk), barrier-free rows
// ---------------------------------------------------------------------------
__global__ __launch_bounds__(256) void k2_alpha_fill(
    const int* __restrict__ c2_seq,
    const float* __restrict__ W1, const float* __restrict__ b1,
    const float* __restrict__ W2, const float* __restrict__ b2,
    const float* __restrict__ vals_ws, const float* __restrict__ h_seq,
    float* __restrict__ out_alpha, float* __restrict__ out_c2)
{
  const int tid = threadIdx.x;
  if (blockIdx.x < NACH * B_) {
    // ------------------ alpha ------------------
    const int b = blockIdx.x >> 2, c = blockIdx.x & 3;
    const int sbeg = c * ACH, send = sbeg + ACH;
    __shared__ float4 hb4[2][DV_ / 4];
    __shared__ float red[4];
    const int grp = tid >> 7, d = tid & 127;
    float w1r[DV_];
    {
      const float4* wr = reinterpret_cast<const float4*>(W1 + (size_t)d * DV_);
#pragma unroll
      for (int k = 0; k < DV_ / 4; ++k) {
        float4 t4 = wr[k];
        w1r[4 * k] = t4.x; w1r[4 * k + 1] = t4.y;
        w1r[4 * k + 2] = t4.z; w1r[4 * k + 3] = t4.w;
      }
    }
    const float b1v = b1[d], w2v = W2[d], b2v = b2[0];
    float* hb = reinterpret_cast<float*>(hb4[grp]);
    for (int s = sbeg; s < send; s += 2) {
      const int ss = s + grp;
      hb[d] = h_seq[((size_t)(b * S_ + ss)) * DV_ + d];
      __syncthreads();
      float y0 = b1v, y1 = 0, y2 = 0, y3 = 0;
#pragma unroll
      for (int k = 0; k < DV_ / 4; ++k) {
        float4 hv = hb4[grp][k];
        y0 += w1r[4 * k + 0] * hv.x; y1 += w1r[4 * k + 1] * hv.y;
        y2 += w1r[4 * k + 2] * hv.z; y3 += w1r[4 * k + 3] * hv.w;
      }
      float part = w2v * fmaxf((y0 + y1) + (y2 + y3), 0.f);
#pragma unroll
      for (int off = 1; off < 64; off <<= 1) part += __shfl_xor(part, off);
      if ((tid & 63) == 0) red[tid >> 6] = part;
      __syncthreads();
      if (d == 0) out_alpha[b * S_ + ss] = red[2 * grp] + red[2 * grp + 1] + b2v;
      __syncthreads();
    }
  } else {
    // ------------------ C2_seq fill ------------------
    const int blk = blockIdx.x - NACH * B_;
    const int b = blk / NFCH, c = blk % NFCH;
    const int s0 = c * FCH;
    __shared__ float vls[S_];
    __shared__ int jl[S_];
    for (int i = tid; i < S_; i += 256) {
      vls[i] = vals_ws[b * S_ + i];
      jl[i] = c2_seq[b * S_ + i];
    }
    __syncthreads();
    // thread owns 16 columns: float4 indices f = tid + jj*256
    f4v v0 = {0.f, 0.f, 0.f, 0.f}, v1 = v0, v2 = v0, v3 = v0;

#define APPLY_EVT(T)                                                          \
    {                                                                         \
      const int j_ = jl[(T)];                                                 \
      const int f_ = j_ >> 2;                                                 \
      if ((f_ & 255) == tid) {                                                \
        const float vv_ = vls[(T)];                                           \
        const int rr_ = f_ >> 8, q_ = j_ & 3;                                 \
        if (rr_ == 0) {                                                       \
          if (q_ == 0) v0.x = vv_; else if (q_ == 1) v0.y = vv_;              \
          else if (q_ == 2) v0.z = vv_; else v0.w = vv_;                      \
        } else if (rr_ == 1) {                                                \
          if (q_ == 0) v1.x = vv_; else if (q_ == 1) v1.y = vv_;              \
          else if (q_ == 2) v1.z = vv_; else v1.w = vv_;                      \
        } else if (rr_ == 2) {                                                \
          if (q_ == 0) v2.x = vv_; else if (q_ == 1) v2.y = vv_;              \
          else if (q_ == 2) v2.z = vv_; else v2.w = vv_;                      \
        } else {                                                              \
          if (q_ == 0) v3.x = vv_; else if (q_ == 1) v3.y = vv_;              \
          else if (q_ == 2) v3.z = vv_; else v3.w = vv_;                      \
        }                                                                     \
      }                                                                       \
    }

    // replay events before the chunk (in order -> last-writer-wins)
    for (int t = 0; t < s0; ++t) APPLY_EVT(t);

    f4v* dst4 = reinterpret_cast<f4v*>(out_c2 + (size_t)b * S_ * NC2_);
    for (int s = s0; s < s0 + FCH; ++s) {
      APPLY_EVT(s);
      f4v* drow = dst4 + (size_t)s * (NC2_ / 4);
      __builtin_nontemporal_store(v0, drow + tid);
      __builtin_nontemporal_store(v1, drow + tid + 256);
      __builtin_nontemporal_store(v2, drow + tid + 512);
      __builtin_nontemporal_store(v3, drow + tid + 768);
    }
#undef APPLY_EVT
  }
}

extern "C" void kernel_launch(void* const* d_in, const int* in_sizes, int n_in,
                              void* d_out, int out_size, void* d_ws, size_t ws_size,
                              hipStream_t stream) {
  const int* c2_seq = (const int*)d_in[1];
  const int* d_seq = (const int*)d_in[3];
  const int* r_seq = (const int*)d_in[4];
  const float* D_emb = (const float*)d_in[5];
  const float* v_d = (const float*)d_in[6];
  const float* v_c2 = (const float*)d_in[7];
  const float* R_emb = (const float*)d_in[8];
  const float* W_ih = (const float*)d_in[9];
  const float* W_hh = (const float*)d_in[10];
  const float* b_ih = (const float*)d_in[11];
  const float* b_hh = (const float*)d_in[12];
  const float* W1 = (const float*)d_in[13];
  const float* b1 = (const float*)d_in[14];
  const float* W2 = (const float*)d_in[15];
  const float* b2 = (const float*)d_in[16];
  const float* W3 = (const float*)d_in[17];
  const float* b3 = (const float*)d_in[18];
  const float* W4 = (const float*)d_in[19];
  const float* b4 = (const float*)d_in[20];

  float* out = (float*)d_out;
  float* out_alpha = out;                                  // [B,S]
  float* out_h = out + B_ * S_;                            // [B,S,DV]
  float* out_c2 = out + B_ * S_ + (size_t)B_ * S_ * DV_;   // [B,S,NC2]
  float* vals_ws = (float*)d_ws;                           // [B*S] floats

  k1_gru_scan<<<dim3(2 * B_), dim3(768), 0, stream>>>(
      c2_seq, d_seq, r_seq, D_emb, v_d, v_c2, R_emb, W_ih, W_hh, b_ih, b_hh,
      W3, b3, W4, b4, out_h, vals_ws);
  k2_alpha_fill<<<dim3(NACH * B_ + B_ * NFCH), dim3(256), 0, stream>>>(
      c2_seq, W1, b1, W2, b2, vals_ws, out_h, out_alpha, out_c2);
}

// Round 3
// 215.236 us; speedup vs baseline: 1.4900x; 1.3458x over previous
//
#include <hip/hip_runtime.h>

namespace {
constexpr int B_ = 64, S_ = 200, DV_ = 128, NC2_ = 4096;
constexpr int FCH = 8, NFCH = 25;    // fill: 25 chunks x 8 rows
constexpr int ACH = 50, NACH = 4;    // alpha: 4 chunks x 50 rows
}

typedef float f4v __attribute__((ext_vector_type(4)));
typedef _Float16 h2v __attribute__((ext_vector_type(2)));

#if defined(__has_builtin)
#if __has_builtin(__builtin_amdgcn_fdot2)
#define HAVE_FDOT2 1
#endif
#endif

__device__ __forceinline__ float dot2acc(h2v a, h2v b, float c) {
#ifdef HAVE_FDOT2
  return __builtin_amdgcn_fdot2(a, b, c, false);
#else
  return c + (float)a.x * (float)b.x + (float)a.y * (float)b.y;
#endif
}

// ---------------------------------------------------------------------------
// K1: blocks [0,64):  GRU per batch, 128 threads, thread d owns gate rows
//                     d, d+128, d+256 -> zero cross-thread exchange per step.
//     blocks [64,128): C2 value scan per batch, single wave, barrier-free.
// ---------------------------------------------------------------------------
__global__ __launch_bounds__(128, 1) void k1_gru_scan(
    const int* __restrict__ c2_seq, const int* __restrict__ d_seq,
    const int* __restrict__ r_seq, const float* __restrict__ D_emb,
    const float* __restrict__ v_d, const float* __restrict__ v_c2,
    const float* __restrict__ R_emb,
    const float* __restrict__ W_ih, const float* __restrict__ W_hh,
    const float* __restrict__ b_ih, const float* __restrict__ b_hh,
    const float* __restrict__ W3, const float* __restrict__ b3,
    const float* __restrict__ W4, const float* __restrict__ b4,
    float* __restrict__ out_h, float* __restrict__ vals_ws)
{
  const int tid = threadIdx.x;
  if (blockIdx.x < B_) {
    // ------------------ GRU for batch b ------------------
    const int b = blockIdx.x;
    __shared__ __align__(16) _Float16 hh[2][DV_];  // double-buffered f16 h
    __shared__ float gl[S_];
    __shared__ int rl[S_];

    for (int i = tid; i < S_; i += 128) {
      gl[i] = D_emb[d_seq[b * S_ + i]];
      rl[i] = r_seq[b * S_ + i];
    }
    const int d = tid;  // 0..127
    // W_hh rows {d, d+128, d+256} as packed f16 pairs: 3 x 64 dwords
    h2v w[3][64];
#pragma unroll
    for (int g = 0; g < 3; ++g) {
      const float4* wr =
          reinterpret_cast<const float4*>(W_hh + (size_t)(d + g * DV_) * DV_);
#pragma unroll
      for (int k = 0; k < 32; ++k) {
        float4 t4 = wr[k];
        h2v lo, hi;
        lo.x = (_Float16)t4.x; lo.y = (_Float16)t4.y;
        hi.x = (_Float16)t4.z; hi.y = (_Float16)t4.w;
        w[g][2 * k] = lo; w[g][2 * k + 1] = hi;
      }
    }
    // collapsed input projections per gate row: xw = gamma*u + p_{r} (incl b_ih)
    float u[3], p0[3], p1[3], bh[3];
#pragma unroll
    for (int g = 0; g < 3; ++g) {
      const int row = d + g * DV_;
      const float4* wi =
          reinterpret_cast<const float4*>(W_ih + (size_t)row * 2 * DV_);
      const float4* vd4 = reinterpret_cast<const float4*>(v_d);
      const float4* re4 = reinterpret_cast<const float4*>(R_emb);
      float uu = 0.f, pp0 = 0.f, pp1 = 0.f;
#pragma unroll 8
      for (int k = 0; k < DV_ / 4; ++k) {
        float4 a = wi[k], vv = vd4[k];
        uu += a.x * vv.x + a.y * vv.y + a.z * vv.z + a.w * vv.w;
        float4 c = wi[DV_ / 4 + k];
        float4 r0 = re4[k], r1 = re4[DV_ / 4 + k];
        pp0 += c.x * r0.x + c.y * r0.y + c.z * r0.z + c.w * r0.w;
        pp1 += c.x * r1.x + c.y * r1.y + c.z * r1.z + c.w * r1.w;
      }
      const float bi = b_ih[row];
      u[g] = uu; p0[g] = pp0 + bi; p1[g] = pp1 + bi;
      bh[g] = b_hh[row];
    }
    float hreg = 0.f;
    hh[0][d] = (_Float16)0.f;
    __syncthreads();

    float* outp = out_h + (size_t)b * S_ * DV_ + d;
    for (int t = 0; t < S_; ++t) {
      const float gv = gl[t];
      const int rv = rl[t];
      const float xr = gv * u[0] + (rv ? p1[0] : p0[0]);
      const float xz = gv * u[1] + (rv ? p1[1] : p0[1]);
      const float xn = gv * u[2] + (rv ? p1[2] : p0[2]);
      const float4* hb = reinterpret_cast<const float4*>(hh[t & 1]);
      float a0 = 0.f, a1 = 0.f, a2 = 0.f;
#pragma unroll
      for (int k = 0; k < 16; ++k) {
        float4 hv = hb[k];  // uniform address -> LDS broadcast
        h2v h0 = __builtin_bit_cast(h2v, hv.x);
        h2v h1 = __builtin_bit_cast(h2v, hv.y);
        h2v h2 = __builtin_bit_cast(h2v, hv.z);
        h2v h3 = __builtin_bit_cast(h2v, hv.w);
        a0 = dot2acc(w[0][4 * k + 0], h0, a0);
        a0 = dot2acc(w[0][4 * k + 1], h1, a0);
        a0 = dot2acc(w[0][4 * k + 2], h2, a0);
        a0 = dot2acc(w[0][4 * k + 3], h3, a0);
        a1 = dot2acc(w[1][4 * k + 0], h0, a1);
        a1 = dot2acc(w[1][4 * k + 1], h1, a1);
        a1 = dot2acc(w[1][4 * k + 2], h2, a1);
        a1 = dot2acc(w[1][4 * k + 3], h3, a1);
        a2 = dot2acc(w[2][4 * k + 0], h0, a2);
        a2 = dot2acc(w[2][4 * k + 1], h1, a2);
        a2 = dot2acc(w[2][4 * k + 2], h2, a2);
        a2 = dot2acc(w[2][4 * k + 3], h3, a2);
      }
      const float r = 1.f / (1.f + __expf(-(xr + a0 + bh[0])));
      const float z = 1.f / (1.f + __expf(-(xz + a1 + bh[1])));
      const float nx = xn + r * (a2 + bh[2]);
      const float e2 = __expf(2.f * nx);
      const float n = (e2 - 1.f) / (e2 + 1.f);
      const float hnew = (1.f - z) * n + z * hreg;
      hreg = hnew;
      outp[(size_t)t * DV_] = hnew;
      hh[(t + 1) & 1][d] = (_Float16)hnew;
      __syncthreads();
    }
  } else {
    // ------------------ C2 value scan, single wave ------------------
    const int b = blockIdx.x - B_;
    __shared__ float C2s[NC2_];
    __shared__ float gl[S_];
    __shared__ int rl[S_];
    __shared__ int jl[S_];
    for (int i = tid; i < NC2_; i += 128) C2s[i] = 0.f;
    for (int i = tid; i < S_; i += 128) {
      gl[i] = D_emb[d_seq[b * S_ + i]];
      rl[i] = r_seq[b * S_ + i];
      jl[i] = c2_seq[b * S_ + i];
    }
    __syncthreads();
    if (tid >= 64) return;
    const int lane = tid;
    float a3L = 0, u3L = 0, q0L = 0, q1L = 0;
    float a3H = 0, u3H = 0, q0H = 0, q1H = 0;
    {
      const float4* vc4 = reinterpret_cast<const float4*>(v_c2);
      const float4* vd4 = reinterpret_cast<const float4*>(v_d);
      const float4* re4 = reinterpret_cast<const float4*>(R_emb);
      const float4* wL = reinterpret_cast<const float4*>(W3 + (size_t)lane * 3 * DV_);
      const float4* wH = reinterpret_cast<const float4*>(W3 + (size_t)(lane + 64) * 3 * DV_);
#pragma unroll 8
      for (int k = 0; k < DV_ / 4; ++k) {
        float4 cc = vc4[k], dd = vd4[k];
        float4 r0 = re4[k], r1 = re4[DV_ / 4 + k];
        float4 aL = wL[k], aH = wH[k];
        a3L += aL.x * cc.x + aL.y * cc.y + aL.z * cc.z + aL.w * cc.w;
        a3H += aH.x * cc.x + aH.y * cc.y + aH.z * cc.z + aH.w * cc.w;
        float4 bL = wL[DV_ / 4 + k], bH = wH[DV_ / 4 + k];
        u3L += bL.x * dd.x + bL.y * dd.y + bL.z * dd.z + bL.w * dd.w;
        u3H += bH.x * dd.x + bH.y * dd.y + bH.z * dd.z + bH.w * dd.w;
        float4 cL = wL[2 * (DV_ / 4) + k], cH = wH[2 * (DV_ / 4) + k];
        q0L += cL.x * r0.x + cL.y * r0.y + cL.z * r0.z + cL.w * r0.w;
        q1L += cL.x * r1.x + cL.y * r1.y + cL.z * r1.z + cL.w * r1.w;
        q0H += cH.x * r0.x + cH.y * r0.y + cH.z * r0.z + cH.w * r0.w;
        q1H += cH.x * r1.x + cH.y * r1.y + cH.z * r1.z + cH.w * r1.w;
      }
      float bbL = b3[lane], bbH = b3[lane + 64];
      q0L += bbL; q1L += bbL; q0H += bbH; q1H += bbH;
    }
    const float w4L = W4[lane], w4H = W4[lane + 64];
    const float b4v = b4[0];

    int jc = jl[0];
    float gv = gl[0];
    int rv = rl[0];
    float pf = 0.f;
    float lastv = 0.f;
    int lastj = -1;
    for (int t = 0; t < S_; ++t) {
      const int tn = (t + 1 < S_) ? t + 1 : 0;
      const int jn = jl[tn];
      const float gvn = gl[tn];
      const int rvn = rl[tn];
      const float pfn = C2s[jn];   // prefetch; patched via lastj/lastv
      const float beta = (jc == lastj) ? lastv : pf;
      float hL = beta * a3L + gv * u3L + (rv ? q1L : q0L);
      float hH = beta * a3H + gv * u3H + (rv ? q1H : q0H);
      float part = fmaxf(hL, 0.f) * w4L + fmaxf(hH, 0.f) * w4H;
#pragma unroll
      for (int off = 1; off < 64; off <<= 1) part += __shfl_xor(part, off);
      const float val = part + b4v;
      if (lane == 0) {
        C2s[jc] = val;
        vals_ws[b * S_ + t] = val;
      }
      lastj = jc; lastv = val;
      jc = jn; gv = gvn; rv = rvn; pf = pfn;
    }
  }
}

// ---------------------------------------------------------------------------
// K2: blocks [0,256):    alpha MLP, (b, 50-row chunk)
//     blocks [256,1856): C2_seq fill, (b, 8-row chunk), barrier-free rows
// ---------------------------------------------------------------------------
__global__ __launch_bounds__(256) void k2_alpha_fill(
    const int* __restrict__ c2_seq,
    const float* __restrict__ W1, const float* __restrict__ b1,
    const float* __restrict__ W2, const float* __restrict__ b2,
    const float* __restrict__ vals_ws, const float* __restrict__ h_seq,
    float* __restrict__ out_alpha, float* __restrict__ out_c2)
{
  const int tid = threadIdx.x;
  if (blockIdx.x < NACH * B_) {
    // ------------------ alpha ------------------
    const int b = blockIdx.x >> 2, c = blockIdx.x & 3;
    const int sbeg = c * ACH, send = sbeg + ACH;
    __shared__ float4 hb4[2][DV_ / 4];
    __shared__ float red[4];
    const int grp = tid >> 7, d = tid & 127;
    float w1r[DV_];
    {
      const float4* wr = reinterpret_cast<const float4*>(W1 + (size_t)d * DV_);
#pragma unroll
      for (int k = 0; k < DV_ / 4; ++k) {
        float4 t4 = wr[k];
        w1r[4 * k] = t4.x; w1r[4 * k + 1] = t4.y;
        w1r[4 * k + 2] = t4.z; w1r[4 * k + 3] = t4.w;
      }
    }
    const float b1v = b1[d], w2v = W2[d], b2v = b2[0];
    float* hb = reinterpret_cast<float*>(hb4[grp]);
    for (int s = sbeg; s < send; s += 2) {
      const int ss = s + grp;
      hb[d] = h_seq[((size_t)(b * S_ + ss)) * DV_ + d];
      __syncthreads();
      float y0 = b1v, y1 = 0, y2 = 0, y3 = 0;
#pragma unroll
      for (int k = 0; k < DV_ / 4; ++k) {
        float4 hv = hb4[grp][k];
        y0 += w1r[4 * k + 0] * hv.x; y1 += w1r[4 * k + 1] * hv.y;
        y2 += w1r[4 * k + 2] * hv.z; y3 += w1r[4 * k + 3] * hv.w;
      }
      float part = w2v * fmaxf((y0 + y1) + (y2 + y3), 0.f);
#pragma unroll
      for (int off = 1; off < 64; off <<= 1) part += __shfl_xor(part, off);
      if ((tid & 63) == 0) red[tid >> 6] = part;
      __syncthreads();
      if (d == 0) out_alpha[b * S_ + ss] = red[2 * grp] + red[2 * grp + 1] + b2v;
      __syncthreads();
    }
  } else {
    // ------------------ C2_seq fill ------------------
    const int blk = blockIdx.x - NACH * B_;
    const int b = blk / NFCH, c = blk % NFCH;
    const int s0 = c * FCH;
    __shared__ float vls[S_];
    __shared__ int jl[S_];
    for (int i = tid; i < S_; i += 256) {
      vls[i] = vals_ws[b * S_ + i];
      jl[i] = c2_seq[b * S_ + i];
    }
    __syncthreads();
    // thread owns 16 columns: float4 indices f = tid + jj*256
    f4v v0 = {0.f, 0.f, 0.f, 0.f}, v1 = v0, v2 = v0, v3 = v0;

#define APPLY_EVT(T)                                                          \
    {                                                                         \
      const int j_ = jl[(T)];                                                 \
      const int f_ = j_ >> 2;                                                 \
      if ((f_ & 255) == tid) {                                                \
        const float vv_ = vls[(T)];                                           \
        const int rr_ = f_ >> 8, q_ = j_ & 3;                                 \
        if (rr_ == 0) {                                                       \
          if (q_ == 0) v0.x = vv_; else if (q_ == 1) v0.y = vv_;              \
          else if (q_ == 2) v0.z = vv_; else v0.w = vv_;                      \
        } else if (rr_ == 1) {                                                \
          if (q_ == 0) v1.x = vv_; else if (q_ == 1) v1.y = vv_;              \
          else if (q_ == 2) v1.z = vv_; else v1.w = vv_;                      \
        } else if (rr_ == 2) {                                                \
          if (q_ == 0) v2.x = vv_; else if (q_ == 1) v2.y = vv_;              \
          else if (q_ == 2) v2.z = vv_; else v2.w = vv_;                      \
        } else {                                                              \
          if (q_ == 0) v3.x = vv_; else if (q_ == 1) v3.y = vv_;              \
          else if (q_ == 2) v3.z = vv_; else v3.w = vv_;                      \
        }                                                                     \
      }                                                                       \
    }

    for (int t = 0; t < s0; ++t) APPLY_EVT(t);

    f4v* dst4 = reinterpret_cast<f4v*>(out_c2 + (size_t)b * S_ * NC2_);
    for (int s = s0; s < s0 + FCH; ++s) {
      APPLY_EVT(s);
      f4v* drow = dst4 + (size_t)s * (NC2_ / 4);
      __builtin_nontemporal_store(v0, drow + tid);
      __builtin_nontemporal_store(v1, drow + tid + 256);
      __builtin_nontemporal_store(v2, drow + tid + 512);
      __builtin_nontemporal_store(v3, drow + tid + 768);
    }
#undef APPLY_EVT
  }
}

extern "C" void kernel_launch(void* const* d_in, const int* in_sizes, int n_in,
                              void* d_out, int out_size, void* d_ws, size_t ws_size,
                              hipStream_t stream) {
  const int* c2_seq = (const int*)d_in[1];
  const int* d_seq = (const int*)d_in[3];
  const int* r_seq = (const int*)d_in[4];
  const float* D_emb = (const float*)d_in[5];
  const float* v_d = (const float*)d_in[6];
  const float* v_c2 = (const float*)d_in[7];
  const float* R_emb = (const float*)d_in[8];
  const float* W_ih = (const float*)d_in[9];
  const float* W_hh = (const float*)d_in[10];
  const float* b_ih = (const float*)d_in[11];
  const float* b_hh = (const float*)d_in[12];
  const float* W1 = (const float*)d_in[13];
  const float* b1 = (const float*)d_in[14];
  const float* W2 = (const float*)d_in[15];
  const float* b2 = (const float*)d_in[16];
  const float* W3 = (const float*)d_in[17];
  const float* b3 = (const float*)d_in[18];
  const float* W4 = (const float*)d_in[19];
  const float* b4 = (const float*)d_in[20];

  float* out = (float*)d_out;
  float* out_alpha = out;                                  // [B,S]
  float* out_h = out + B_ * S_;                            // [B,S,DV]
  float* out_c2 = out + B_ * S_ + (size_t)B_ * S_ * DV_;   // [B,S,NC2]
  float* vals_ws = (float*)d_ws;                           // [B*S] floats

  k1_gru_scan<<<dim3(2 * B_), dim3(128), 0, stream>>>(
      c2_seq, d_seq, r_seq, D_emb, v_d, v_c2, R_emb, W_ih, W_hh, b_ih, b_hh,
      W3, b3, W4, b4, out_h, vals_ws);
  k2_alpha_fill<<<dim3(NACH * B_ + B_ * NFCH), dim3(256), 0, stream>>>(
      c2_seq, W1, b1, W2, b2, vals_ws, out_h, out_alpha, out_c2);
}